// Round 8
// baseline (176.355 us; speedup 1.0000x reference)
//
#include <hip/hip_runtime.h>
#include <math.h>

#define NSTATE 64
#define LEN    4096
#define NH     256
#define NB     16

typedef float f2 __attribute__((ext_vector_type(2)));

// K in base-8 digit-reversed order (fftconv consumption order).
// Position p holds natural frequency rev8_12(p) (rev8_12 is an involution).
__device__ f2 g_ksym[NH * LEN];

__device__ __forceinline__ int rev8_12(int p) {
  return ((p & 7) << 9) | (((p >> 3) & 7) << 6) | (((p >> 6) & 7) << 3) | (p >> 9);
}

__device__ __forceinline__ f2 mkf2(float a, float b){ f2 r; r.x = a; r.y = b; return r; }

// ---------------- packed-f32 complex primitives (VOP3P) ----------------
__device__ __forceinline__ f2 cmul_pk(f2 a, f2 b) {
  f2 t, r;
  asm("v_pk_mul_f32 %0, %1, %2 op_sel:[0,0] op_sel_hi:[0,1]"
      : "=v"(t) : "v"(a), "v"(b));
  asm("v_pk_fma_f32 %0, %1, %2, %3 op_sel:[1,1,0] op_sel_hi:[1,0,1] neg_lo:[0,1,0]"
      : "=v"(r) : "v"(a), "v"(b), "v"(t));
  return r;
}
__device__ __forceinline__ f2 cmulc_pk(f2 a, f2 b) {
  f2 t, r;
  asm("v_pk_mul_f32 %0, %1, %2 op_sel:[0,0] op_sel_hi:[0,1] neg_hi:[0,1]"
      : "=v"(t) : "v"(a), "v"(b));
  asm("v_pk_fma_f32 %0, %1, %2, %3 op_sel:[1,1,0] op_sel_hi:[1,0,1]"
      : "=v"(r) : "v"(a), "v"(b), "v"(t));
  return r;
}
__device__ __forceinline__ void cmac_pk(f2& acc, f2 v, f2 e) {
  asm("v_pk_fma_f32 %0, %1, %2, %0 op_sel:[0,0,0] op_sel_hi:[0,1,1]"
      : "+v"(acc) : "v"(v), "v"(e));
  asm("v_pk_fma_f32 %0, %1, %2, %0 op_sel:[1,1,0] op_sel_hi:[1,0,1] neg_lo:[0,1,0]"
      : "+v"(acc) : "v"(v), "v"(e));
}
__device__ __forceinline__ void pk_fma(f2& acc, f2 a, f2 b) {
  asm("v_pk_fma_f32 %0, %1, %2, %0" : "+v"(acc) : "v"(a), "v"(b));
}

#define RSQ2 0.70710678118654752f

__device__ __forceinline__ void bfly8_fwd(f2 v[8]) {
  f2 a0 = v[0] + v[4], b0 = v[0] - v[4];
  f2 a1 = v[1] + v[5], d1 = v[1] - v[5];
  f2 a2 = v[2] + v[6], d2 = v[2] - v[6];
  f2 a3 = v[3] + v[7], d3 = v[3] - v[7];
  f2 b1 = mkf2(RSQ2 * (d1.x + d1.y), RSQ2 * (d1.y - d1.x));
  f2 b3 = mkf2(RSQ2 * (d3.y - d3.x), -RSQ2 * (d3.x + d3.y));
  f2 u0 = a0 + a2, u1 = a0 - a2, u2 = a1 + a3, u3 = a1 - a3;
  v[0] = u0 + u2;
  v[2] = mkf2(u1.x + u3.y, u1.y - u3.x);
  v[4] = u0 - u2;
  v[6] = mkf2(u1.x - u3.y, u1.y + u3.x);
  f2 w0 = mkf2(b0.x + d2.y, b0.y - d2.x);
  f2 w1 = mkf2(b0.x - d2.y, b0.y + d2.x);
  f2 w2 = b1 + b3, w3 = b1 - b3;
  v[1] = w0 + w2;
  v[3] = mkf2(w1.x + w3.y, w1.y - w3.x);
  v[5] = w0 - w2;
  v[7] = mkf2(w1.x - w3.y, w1.y + w3.x);
}

__device__ __forceinline__ void bfly8_inv(f2 v[8]) {
  f2 a0 = v[0] + v[4], b0 = v[0] - v[4];
  f2 a1 = v[1] + v[5], d1 = v[1] - v[5];
  f2 a2 = v[2] + v[6], d2 = v[2] - v[6];
  f2 a3 = v[3] + v[7], d3 = v[3] - v[7];
  f2 b1 = mkf2(RSQ2 * (d1.x - d1.y), RSQ2 * (d1.x + d1.y));
  f2 b3 = mkf2(-RSQ2 * (d3.x + d3.y), RSQ2 * (d3.x - d3.y));
  f2 u0 = a0 + a2, u1 = a0 - a2, u2 = a1 + a3, u3 = a1 - a3;
  v[0] = u0 + u2;
  v[2] = mkf2(u1.x - u3.y, u1.y + u3.x);
  v[4] = u0 - u2;
  v[6] = mkf2(u1.x + u3.y, u1.y - u3.x);
  f2 w0 = mkf2(b0.x - d2.y, b0.y + d2.x);
  f2 w1 = mkf2(b0.x + d2.y, b0.y - d2.x);
  f2 w2 = b1 + b3, w3 = b1 - b3;
  v[1] = w0 + w2;
  v[3] = mkf2(w1.x - w3.y, w1.y + w3.x);
  v[5] = w0 - w2;
  v[7] = mkf2(w1.x + w3.y, w1.y - w3.x);
}

// forward twiddle: v[m] *= w1^m
__device__ __forceinline__ void twiddle7(f2 v[8], f2 w1) {
  f2 w2 = cmul_pk(w1, w1);
  f2 w3 = cmul_pk(w2, w1);
  f2 w4 = cmul_pk(w2, w2);
  f2 w5 = cmul_pk(w3, w2);
  f2 w6 = cmul_pk(w3, w3);
  f2 w7 = cmul_pk(w4, w3);
  v[1] = cmul_pk(v[1], w1); v[2] = cmul_pk(v[2], w2); v[3] = cmul_pk(v[3], w3);
  v[4] = cmul_pk(v[4], w4); v[5] = cmul_pk(v[5], w5); v[6] = cmul_pk(v[6], w6);
  v[7] = cmul_pk(v[7], w7);
}
// inverse twiddle: v[m] *= conj(w1^m)
__device__ __forceinline__ void twiddle7c(f2 v[8], f2 w1) {
  f2 w2 = cmul_pk(w1, w1);
  f2 w3 = cmul_pk(w2, w1);
  f2 w4 = cmul_pk(w2, w2);
  f2 w5 = cmul_pk(w3, w2);
  f2 w6 = cmul_pk(w3, w3);
  f2 w7 = cmul_pk(w4, w3);
  v[1] = cmulc_pk(v[1], w1); v[2] = cmulc_pk(v[2], w2); v[3] = cmulc_pk(v[3], w3);
  v[4] = cmulc_pk(v[4], w4); v[5] = cmulc_pk(v[5], w5); v[6] = cmulc_pk(v[6], w6);
  v[7] = cmulc_pk(v[7], w7);
}

#define WAVE_SYNC() asm volatile("s_waitcnt lgkmcnt(0)" ::: "memory")

// ---------------- frequency-domain S4 kernel (prep fused, LDS params, 4 pts) ----
// Grid NH*4 x 256. XCD-chunked bid swizzle: with round-robin HW dispatch
// (XCD = bid&7), logical blocks [128c,128(c+1)) land on XCD c, i.e. h in
// [32c, 32(c+1)). The 4 blocks of each h share one XCD's L2, so the
// rev8_12-scattered 8-B K-writes COMBINE into full 64-B lines in L2 before
// eviction (WRITE_SIZE was 31 MB for 8 MB of K = 4x amplification).
// Same h->XCD map as s4_fftconv so K is re-read from the same L2.
__global__ __launch_bounds__(256) void s4_kernel_freq(
    const float* __restrict__ Lre, const float* __restrict__ Lim,
    const float* __restrict__ Pre, const float* __restrict__ Pim,
    const float* __restrict__ Bre, const float* __restrict__ Bim,
    const float* __restrict__ Cre, const float* __restrict__ Cim,
    const float* __restrict__ log_step)
{
  __shared__ float4 sLam[NSTATE];
  __shared__ float4 sV01[NSTATE];
  __shared__ f2     sV2[NSTATE];

  const int bid = blockIdx.x;
  const int L = ((bid & 7) << 7) | (bid >> 3);   // bijective XCD-chunk swizzle
  const int h = L >> 2;
  const int q = ((L & 3) << 8) | threadIdx.x;    // 0..1023

  if (threadIdx.x < NSTATE) {
    int idx = h * NSTATE + threadIdx.x;
    float lr = Lre[idx], li = Lim[idx];
    float pr = Pre[idx], pi = Pim[idx];
    float br = Bre[idx], bi = Bim[idx];
    float cr = Cre[idx], ci = Cim[idx];
    float pp = pr * pr + pi * pi;
    sLam[threadIdx.x] = make_float4(lr, li, pp, pp);
    sV01[threadIdx.x] = make_float4(cr * br + ci * bi, cr * bi - ci * br,
                                    cr * pr + ci * pi, cr * pi - ci * pr);
    sV2[threadIdx.x] = mkf2(pr * br + pi * bi, pr * bi - pi * br);
  }

  const float step = expf(log_step[h]);
  const float ts = 2.0f / step;
  const float NEG2PI = -6.2831853071795864769f;

  float gar, gai, car, cai, gbr, gbi, cbr, cbi;
  float gcr, gci, ccr, cci, gdr, gdi, cdr, cdi;
  {
    float so, co;
    sincosf(NEG2PI * ((float)q * (1.0f / (float)LEN)), &so, &co);
    float dr = 1.0f + co, di = so;
    float inv = 1.0f / fmaf(dr, dr, di * di);
    car = 2.0f * dr * inv; cai = -2.0f * di * inv;
    float nr = 1.0f - co, ni = -so;
    gar = ts * (fmaf(nr, dr, ni * di) * inv);
    gai = ts * (fmaf(ni, dr, -nr * di) * inv);
  }
  if (q == 0) {           // point B is l = 2048 (self-paired), compute directly
    float so, co;
    sincosf(NEG2PI * 0.5f, &so, &co);
    float dr = 1.0f + co, di = so;
    float inv = 1.0f / fmaf(dr, dr, di * di);
    cbr = 2.0f * dr * inv; cbi = -2.0f * di * inv;
    float nr = 1.0f - co, ni = -so;
    gbr = ts * (fmaf(nr, dr, ni * di) * inv);
    gbi = ts * (fmaf(ni, dr, -nr * di) * inv);
  } else {                // B = mirror of A: Omega -> conj => g,c -> conj
    gbr = gar; gbi = -gai; cbr = car; cbi = -cai;
  }
  {
    float so, co;
    sincosf(NEG2PI * ((float)(q + 1024) * (1.0f / (float)LEN)), &so, &co);
    float dr = 1.0f + co, di = so;
    float inv = 1.0f / fmaf(dr, dr, di * di);
    ccr = 2.0f * dr * inv; cci = -2.0f * di * inv;
    float nr = 1.0f - co, ni = -so;
    gcr = ts * (fmaf(nr, dr, ni * di) * inv);
    gci = ts * (fmaf(ni, dr, -nr * di) * inv);
  }
  gdr = gcr; gdi = -gci; cdr = ccr; cdi = -cci;

  const f2 gA = mkf2(gar, gai), gB = mkf2(gbr, gbi);
  const f2 gC = mkf2(gcr, gci), gD = mkf2(gdr, gdi);

  f2 A00 = {0,0}, A01 = {0,0}, A10 = {0,0}, A11 = {0,0};
  f2 B00 = {0,0}, B01 = {0,0}, B10 = {0,0}, B11 = {0,0};
  f2 C00 = {0,0}, C01 = {0,0}, C10 = {0,0}, C11 = {0,0};
  f2 D00 = {0,0}, D01 = {0,0}, D10 = {0,0}, D11 = {0,0};

  __syncthreads();

#define CAU(g_, k00,k01,k10,k11)                                             \
  {                                                                          \
    f2 d = g_ - lam;                                                         \
    float idn = __builtin_amdgcn_rcpf(fmaf(d.x, d.x, d.y * d.y));            \
    f2 e = mkf2(d.x * idn, -(d.y * idn));                                    \
    cmac_pk(k00, v0, e); cmac_pk(k01, v1, e);                                \
    cmac_pk(k10, v2, e); pk_fma(k11, pp, e);                                 \
  }

#pragma unroll 4
  for (int n = 0; n < NSTATE; ++n) {
    float4 L4 = sLam[n];
    float4 V4 = sV01[n];
    f2 v2 = sV2[n];
    f2 lam = mkf2(L4.x, L4.y);
    f2 pp  = mkf2(L4.z, L4.w);
    f2 v0  = mkf2(V4.x, V4.y);
    f2 v1  = mkf2(V4.z, V4.w);
    CAU(gA, A00, A01, A10, A11)
    CAU(gB, B00, B01, B10, B11)
    CAU(gC, C00, C01, C10, C11)
    CAU(gD, D00, D01, D10, D11)
  }
#undef CAU

#define FINISH(cr_, ci_, k00,k01,k10,k11, Kr, Ki)                            \
  {                                                                          \
    float rr = 1.0f + k11.x, ri = k11.y;                                     \
    float rinv = 1.0f / fmaf(rr, rr, ri * ri);                               \
    float pr_ = k01.x * k10.x - k01.y * k10.y;                               \
    float pi_ = k01.x * k10.y + k01.y * k10.x;                               \
    float wr = (pr_ * rr + pi_ * ri) * rinv;                                 \
    float wi = (pi_ * rr - pr_ * ri) * rinv;                                 \
    float sr = k00.x - wr, si = k00.y - wi;                                  \
    Kr = cr_ * sr - ci_ * si; Ki = cr_ * si + ci_ * sr;                      \
  }

  float Kar, Kai, Kbr, Kbi, Kcr, Kci, Kdr, Kdi;
  FINISH(car, cai, A00, A01, A10, A11, Kar, Kai)
  FINISH(cbr, cbi, B00, B01, B10, B11, Kbr, Kbi)
  FINISH(ccr, cci, C00, C01, C10, C11, Kcr, Kci)
  FINISH(cdr, cdi, D00, D01, D10, D11, Kdr, Kdi)
#undef FINISH

  f2* out = g_ksym + (size_t)h * LEN;
  if (q == 0) {
    out[rev8_12(0)]    = mkf2(Kar, 0.0f);   // Ksym[0]    = Re K[0]
    out[rev8_12(2048)] = mkf2(Kbr, 0.0f);   // Ksym[2048] = Re K[2048]
  } else {
    float fr = 0.5f * (Kar + Kbr), fi = 0.5f * (Kai - Kbi);
    out[rev8_12(q)]        = mkf2(fr, fi);
    out[rev8_12(LEN - q)]  = mkf2(fr, -fi);  // conj pair
  }
  {
    float fr = 0.5f * (Kcr + Kdr), fi = 0.5f * (Kci - Kdi);
    out[rev8_12(1024 + q)] = mkf2(fr, fi);
    out[rev8_12(3072 - q)] = mkf2(fr, -fi);
  }
}

// ---------------- FFT convolution: register radix-8, 4096 = 8^4 ----------------
// R3 structure (best measured) + XCD-chunked swizzle: the 8 blocks sharing an
// h (and its 32 KB K row) land on ONE XCD (h in [32c,32(c+1)) on XCD c —
// same map as s4_kernel_freq, so the K row may still be L2-resident from its
// producer). u loads / y stores are non-temporal (read-once / write-once
// streaming) so they don't evict K from L2.
__global__ __launch_bounds__(512) void s4_fftconv(const float* __restrict__ u,
                                                 float* __restrict__ y)
{
  __shared__ f2 X[4608];   // 8 waves x 576

  const int t = threadIdx.x;
  const int bid = blockIdx.x;
  const int L = ((bid & 7) << 8) | (bid >> 3);   // bijective XCD-chunk swizzle
  const int h  = L >> 3;        // 0..255, 32 h per XCD
  const int bp = L & 7;         // 0..7

  const int w  = t >> 6;        // wave id == radix-8 stage-1 output digit
  const int i  = t & 63;        // lane within wave
  const int i3 = i >> 3;
  const int i7 = i & 7;
  const int R  = 576 * w;       // private LDS region base

  float c1, s1, c2, s2, c3, s3;
  sincosf((float)t  * (-6.2831853071795864769f / 4096.0f), &s1, &c1);
  sincosf((float)i  * (-6.2831853071795864769f /  512.0f), &s2, &c2);
  sincosf((float)i7 * (-6.2831853071795864769f /   64.0f), &s3, &c3);
  const f2 W1 = mkf2(c1, s1), W2 = mkf2(c2, s2), W3 = mkf2(c3, s3);

  const float* u1 = u + ((size_t)bp * NH + h) * LEN;
  const float* u2 = u + ((size_t)(bp + 8) * NH + h) * LEN;

  f2 v[8];
#pragma unroll
  for (int m = 0; m < 8; ++m)
    v[m] = mkf2(__builtin_nontemporal_load(&u1[t + 512 * m]),
                __builtin_nontemporal_load(&u2[t + 512 * m]));
  bfly8_fwd(v);
  twiddle7(v, W1);
#pragma unroll
  for (int m = 0; m < 8; ++m) X[576 * m + t] = v[m];   // scatter: group m region

  // K fragment: issue before the barrier; consumed only in the mid-stage.
  const float4* kp = (const float4*)(g_ksym + (size_t)h * LEN + 8 * t);
  float4 k0 = kp[0], k1 = kp[1], k2 = kp[2], k3 = kp[3];

  __syncthreads();                                     // block barrier #1

  // ---- stage 2 (stride 64 within group), wave-local from here ----
#pragma unroll
  for (int m = 0; m < 8; ++m) v[m] = X[R + i + 64 * m];
  bfly8_fwd(v);
  twiddle7(v, W2);
#pragma unroll
  for (int m = 0; m < 8; ++m) X[R + 68 * m + i] = v[m];
  WAVE_SYNC();

  // ---- stage 3 (stride 8) ----
#pragma unroll
  for (int m = 0; m < 8; ++m) v[m] = X[R + 68 * i3 + i7 + 8 * m];
  bfly8_fwd(v);
  twiddle7(v, W3);
#pragma unroll
  for (int m = 0; m < 8; ++m) X[R + 9 * (8 * i3 + m) + i7] = v[m];
  WAVE_SYNC();

  // ---- stage 4 fwd + pointwise + stage 4 inv (registers) ----
  {
#pragma unroll
    for (int m = 0; m < 8; ++m) v[m] = X[R + 9 * i + m];
    bfly8_fwd(v);
    v[0] = cmul_pk(v[0], mkf2(k0.x, k0.y));
    v[1] = cmul_pk(v[1], mkf2(k0.z, k0.w));
    v[2] = cmul_pk(v[2], mkf2(k1.x, k1.y));
    v[3] = cmul_pk(v[3], mkf2(k1.z, k1.w));
    v[4] = cmul_pk(v[4], mkf2(k2.x, k2.y));
    v[5] = cmul_pk(v[5], mkf2(k2.z, k2.w));
    v[6] = cmul_pk(v[6], mkf2(k3.x, k3.y));
    v[7] = cmul_pk(v[7], mkf2(k3.z, k3.w));
    bfly8_inv(v);
#pragma unroll
    for (int p = 0; p < 8; ++p) X[R + 9 * i + p] = v[p];
  }
  WAVE_SYNC();

  // ---- stage 3 inverse ----
#pragma unroll
  for (int m = 0; m < 8; ++m) v[m] = X[R + 9 * (8 * i3 + m) + i7];
  twiddle7c(v, W3);
  bfly8_inv(v);
#pragma unroll
  for (int p = 0; p < 8; ++p) X[R + 68 * i3 + i7 + 8 * p] = v[p];
  WAVE_SYNC();

  // ---- stage 2 inverse ----
#pragma unroll
  for (int m = 0; m < 8; ++m) v[m] = X[R + 68 * m + i];
  twiddle7c(v, W2);
  bfly8_inv(v);
#pragma unroll
  for (int p = 0; p < 8; ++p) X[R + i + 64 * p] = v[p];
  __syncthreads();                                     // block barrier #2

  // ---- stage 1 inverse (block-wide gather) ----
#pragma unroll
  for (int m = 0; m < 8; ++m) v[m] = X[576 * m + t];
  twiddle7c(v, W1);
  bfly8_inv(v);

  float* y1 = y + ((size_t)bp * NH + h) * LEN;
  float* y2 = y + ((size_t)(bp + 8) * NH + h) * LEN;
  const float sc = 1.0f / (float)LEN;
#pragma unroll
  for (int p = 0; p < 8; ++p) {
    __builtin_nontemporal_store(v[p].x * sc, &y1[t + 512 * p]);
    __builtin_nontemporal_store(v[p].y * sc, &y2[t + 512 * p]);
  }
}

extern "C" void kernel_launch(void* const* d_in, const int* in_sizes, int n_in,
                              void* d_out, int out_size, void* d_ws, size_t ws_size,
                              hipStream_t stream) {
  const float* u    = (const float*)d_in[0];
  const float* Lre  = (const float*)d_in[1];
  const float* Lim  = (const float*)d_in[2];
  const float* Pre  = (const float*)d_in[3];
  const float* Pim  = (const float*)d_in[4];
  const float* Bre  = (const float*)d_in[5];
  const float* Bim  = (const float*)d_in[6];
  const float* Cre  = (const float*)d_in[7];
  const float* Cim  = (const float*)d_in[8];
  const float* lstep = (const float*)d_in[9];
  float* y = (float*)d_out;

  s4_kernel_freq<<<NH * 4, 256, 0, stream>>>(Lre, Lim, Pre, Pim, Bre, Bim, Cre, Cim, lstep);
  s4_fftconv<<<NH * (NB / 2), 512, 0, stream>>>(u, y);
}